// Round 4
// baseline (131.169 us; speedup 1.0000x reference)
//
#include <hip/hip_runtime.h>

#define N_NODES 100000
#define N_EDGES 3200000
#define DIN     128
#define DOUT    64

typedef unsigned short bf16_t;

__device__ __forceinline__ float bf16_to_f32(bf16_t h) {
    union { unsigned int u; float f; } un;
    un.u = ((unsigned int)h) << 16;
    return un.f;
}
__device__ __forceinline__ bf16_t f32_to_bf16(float f) {
    union { float f; unsigned int u; } un; un.f = f;
    unsigned int u = un.u + 0x7fffu + ((un.u >> 16) & 1u);  // round-nearest-even
    return (bf16_t)(u >> 16);
}

// ---------------------------------------------------------------------------
// Kernel 1: xw_bf16 = bf16(x @ W).  64x64 tile, 4x4 reg blocking, float4 LDS.
// ---------------------------------------------------------------------------
__global__ __launch_bounds__(256) void gemm_xw_bf16(const float* __restrict__ x,
                                                    const float* __restrict__ w,
                                                    bf16_t* __restrict__ xwb) {
    __shared__ float Xs[64][DIN];   // (r,k) lives at float4-index (k/4) ^ (r&7)
    __shared__ float Ws[DIN][DOUT];

    const int tid = threadIdx.x;
    const int block_row = blockIdx.x * 64;

    {
        const float4* w4 = (const float4*)w;
        float4* ws4 = (float4*)Ws;
        for (int i = tid; i < DIN * DOUT / 4; i += 256)
            ws4[i] = w4[i];
    }
    for (int i = tid; i < 64 * DIN / 4; i += 256) {
        const int r  = i >> 5;
        const int k4 = i & 31;
        const int gr = block_row + r;
        float4 v = make_float4(0.f, 0.f, 0.f, 0.f);
        if (gr < N_NODES) v = ((const float4*)x)[gr * (DIN / 4) + k4];
        ((float4*)&Xs[r][0])[k4 ^ (r & 7)] = v;
    }
    __syncthreads();

    const int tx = tid & 15;
    const int ty = tid >> 4;

    float acc[4][4] = {};
#pragma unroll 2
    for (int k4 = 0; k4 < DIN / 4; ++k4) {
        float4 xr[4];
#pragma unroll
        for (int j = 0; j < 4; ++j) {
            const int r = ty * 4 + j;
            xr[j] = ((const float4*)&Xs[r][0])[k4 ^ (r & 7)];
        }
#pragma unroll
        for (int kk = 0; kk < 4; ++kk) {
            const float4 wv = ((const float4*)Ws)[(k4 * 4 + kk) * (DOUT / 4) + tx];
            const float xv0 = (kk == 0) ? xr[0].x : (kk == 1) ? xr[0].y : (kk == 2) ? xr[0].z : xr[0].w;
            const float xv1 = (kk == 0) ? xr[1].x : (kk == 1) ? xr[1].y : (kk == 2) ? xr[1].z : xr[1].w;
            const float xv2 = (kk == 0) ? xr[2].x : (kk == 1) ? xr[2].y : (kk == 2) ? xr[2].z : xr[2].w;
            const float xv3 = (kk == 0) ? xr[3].x : (kk == 1) ? xr[3].y : (kk == 2) ? xr[3].z : xr[3].w;
            acc[0][0] += xv0 * wv.x; acc[0][1] += xv0 * wv.y; acc[0][2] += xv0 * wv.z; acc[0][3] += xv0 * wv.w;
            acc[1][0] += xv1 * wv.x; acc[1][1] += xv1 * wv.y; acc[1][2] += xv1 * wv.z; acc[1][3] += xv1 * wv.w;
            acc[2][0] += xv2 * wv.x; acc[2][1] += xv2 * wv.y; acc[2][2] += xv2 * wv.z; acc[2][3] += xv2 * wv.w;
            acc[3][0] += xv3 * wv.x; acc[3][1] += xv3 * wv.y; acc[3][2] += xv3 * wv.z; acc[3][3] += xv3 * wv.w;
        }
    }

#pragma unroll
    for (int j = 0; j < 4; ++j) {
        const int gr = block_row + ty * 4 + j;
        if (gr < N_NODES) {
            const unsigned int p0 = (unsigned int)f32_to_bf16(acc[j][0]) |
                                    ((unsigned int)f32_to_bf16(acc[j][1]) << 16);
            const unsigned int p1 = (unsigned int)f32_to_bf16(acc[j][2]) |
                                    ((unsigned int)f32_to_bf16(acc[j][3]) << 16);
            uint2 pk; pk.x = p0; pk.y = p1;
            *(uint2*)&xwb[gr * DOUT + tx * 4] = pk;
        }
    }
}

// ---------------------------------------------------------------------------
// Kernel 1b: row_ptr[r] = lower_bound(rows, r) from the SORTED rows array.
// ---------------------------------------------------------------------------
__global__ __launch_bounds__(256) void build_row_ptr(const int* __restrict__ rows,
                                                     int* __restrict__ row_ptr) {
    const int e = blockIdx.x * blockDim.x + threadIdx.x;
    if (e >= N_EDGES) return;
    const int cur  = rows[e];
    const int prev = (e == 0) ? -1 : rows[e - 1];
    for (int r = prev + 1; r <= cur; ++r) row_ptr[r] = e;
    if (e == N_EDGES - 1) {
        for (int r = cur + 1; r <= N_NODES; ++r) row_ptr[r] = N_EDGES;
    }
}

// ---------------------------------------------------------------------------
// Kernel 2: SpMM + combine. One wave per row, lane = feature.
// Unmasked 32-deep gather unroll (32 loads in flight, ~56 VGPR still 8
// waves/SIMD) + masked 16-wide tail so remainders keep MLP. cols/vals are
// wave-uniform -> scalar loads. Nontemporal h0/out streaming.
// ---------------------------------------------------------------------------
__global__ __launch_bounds__(256) void spmm_combine(const bf16_t* __restrict__ xwb,
                                                    const int*    __restrict__ row_ptr,
                                                    const int*    __restrict__ cols,
                                                    const float*  __restrict__ vals,
                                                    const float*  __restrict__ h0,
                                                    const float*  __restrict__ bias,
                                                    float* __restrict__ out) {
    const int wid  = (blockIdx.x * blockDim.x + threadIdx.x) >> 6;
    const int lane = threadIdx.x & 63;
    if (wid >= N_NODES) return;

    const int row   = __builtin_amdgcn_readfirstlane(wid);
    const int start = __builtin_amdgcn_readfirstlane(row_ptr[row]);
    const int end   = __builtin_amdgcn_readfirstlane(row_ptr[row + 1]);

    const float h = __builtin_nontemporal_load(&h0[row * DOUT + lane]);

    if (start == end) {
        __builtin_nontemporal_store(0.1f * h + bias[lane], &out[row * DOUT + lane]);
        return;
    }

    const int c_safe = cols[start];   // valid row index for dead tail slots

    float acc[16] = {};
    int e = start;

    // main: 32 independent gathers in flight
    for (; e + 32 <= end; e += 32) {
        int   c[32];
        float v[32];
#pragma unroll
        for (int u = 0; u < 32; ++u) { c[u] = cols[e + u]; v[u] = vals[e + u]; }
#pragma unroll
        for (int u = 0; u < 32; ++u)
            acc[u & 15] += v[u] * bf16_to_f32(xwb[c[u] * DOUT + lane]);
    }

    // masked 16-wide tail: dead slots load c_safe with v=0 (stays in-bounds)
    for (; e < end; e += 16) {
        int   c[16];
        float v[16];
#pragma unroll
        for (int u = 0; u < 16; ++u) {
            const int  idx = e + u;
            const bool ok  = idx < end;
            const int  idxc = ok ? idx : start;
            c[u] = ok ? cols[idxc] : c_safe;
            v[u] = ok ? vals[idxc] : 0.f;
        }
#pragma unroll
        for (int u = 0; u < 16; ++u)
            acc[u] += v[u] * bf16_to_f32(xwb[c[u] * DOUT + lane]);
    }

    float s = 0.f;
#pragma unroll
    for (int u = 0; u < 8; ++u) s += (acc[u] + acc[u + 8]);

    const float r = 0.9f * s + 0.1f * h + bias[lane];
    __builtin_nontemporal_store(r, &out[row * DOUT + lane]);
}

extern "C" void kernel_launch(void* const* d_in, const int* in_sizes, int n_in,
                              void* d_out, int out_size, void* d_ws, size_t ws_size,
                              hipStream_t stream) {
    const float* x    = (const float*)d_in[0];
    const int*   rows = (const int*)  d_in[1];
    const int*   cols = (const int*)  d_in[2];
    const float* vals = (const float*)d_in[3];
    const float* h0   = (const float*)d_in[4];
    const float* w    = (const float*)d_in[5];
    const float* bias = (const float*)d_in[6];
    float* out = (float*)d_out;

    bf16_t* xwb = (bf16_t*)d_ws;                         // N*DOUT bf16 = 12.8 MB
    const size_t xw_bytes = (size_t)N_NODES * DOUT * sizeof(bf16_t);
    int* row_ptr = (int*)((char*)d_ws + xw_bytes);       // (N+1) ints = 400 KB

    gemm_xw_bf16<<<(N_NODES + 63) / 64, 256, 0, stream>>>(x, w, xwb);
    build_row_ptr<<<(N_EDGES + 255) / 256, 256, 0, stream>>>(rows, row_ptr);
    spmm_combine<<<(N_NODES * DOUT + 255) / 256, 256, 0, stream>>>(
        xwb, row_ptr, cols, vals, h0, bias, out);
}